// Round 6
// baseline (676.599 us; speedup 1.0000x reference)
//
#include <hip/hip_runtime.h>
#include <math.h>

// Problem constants
#define B_   128
#define E_   512
#define H_   512
#define S_   2048
#define V_   83
#define PAD_ 82

typedef float v4f __attribute__((ext_vector_type(4)));
typedef _Float16 h4 __attribute__((ext_vector_type(4)));

__device__ __forceinline__ v4f ldnt4(const float* p) {
    return __builtin_nontemporal_load((const v4f*)p);
}

// ---- one-time prep -------------------------------------------------------

// pe2[e] = pe(e,2); x01i[e*3+{0,1,2}] = {embPAD[e]+pe(e,0), embPAD[e]+pe(e,1), 0}
__global__ void k_misc(const float* __restrict__ emb, float* __restrict__ pe2,
                       float* __restrict__ x01i) {
    int e = threadIdx.x;                              // 1 block, 512 threads
    float freq = expf(-9.210340371976184f * (float)(e & ~1) * (1.0f / 512.0f));
    float p0 = (e & 1) ? 1.0f : 0.0f;                 // cos(0)/sin(0)
    float p1 = (e & 1) ? cosf(freq) : sinf(freq);
    float p2 = (e & 1) ? cosf(2.0f * freq) : sinf(2.0f * freq);
    pe2[e] = p2;
    float ep = emb[PAD_ * 512 + e];
    x01i[e * 3 + 0] = ep + p0;
    x01i[e * 3 + 1] = ep + p1;
    x01i[e * 3 + 2] = 0.0f;
}

// base[o] = dot(conv_w[o, 0:1536], x01i)  — contiguous row reads, wave per o
__global__ void k_base3(const float* __restrict__ cw, const float* __restrict__ x01i,
                        float* __restrict__ base) {
    int t = threadIdx.x, w = t >> 6, lane = t & 63;   // grid 256, block 256
    __shared__ float xs[1536];
    for (int j = t; j < 1536; j += 256) xs[j] = x01i[j];
    __syncthreads();
    int o = blockIdx.x * 4 + w;
    const float* rp = cw + (size_t)o * 1536 + lane * 4;
    float acc = 0.f;
    #pragma unroll
    for (int j = 0; j < 6; ++j) {
        float4 v = *(const float4*)(rp + j * 256);
        const float* xp = &xs[lane * 4 + j * 256];
        acc += v.x * xp[0] + v.y * xp[1] + v.z * xp[2] + v.w * xp[3];
    }
    #pragma unroll
    for (int off = 32; off > 0; off >>= 1) acc += __shfl_down(acc, off, 64);
    if (lane == 0) base[o] = acc;
}

// LDS-tiled transpose: W2t[e*1024 + o] = conv_w[o*1536 + e*3 + 2]
__global__ void k_prep(const float* __restrict__ cw, float* __restrict__ W2t) {
    __shared__ float tile[64][129];                   // +1 pad
    int ob = blockIdx.x * 64, eb = blockIdx.y * 128;
    int t = threadIdx.x;                              // block 256
    for (int idx = t; idx < 8192; idx += 256) {
        int r = idx >> 7, e = idx & 127;
        tile[r][e] = cw[(size_t)(ob + r) * 1536 + (eb + e) * 3 + 2];
    }
    __syncthreads();
    for (int idx = t; idx < 8192; idx += 256) {
        int e = idx >> 6, o = idx & 63;
        W2t[(size_t)(eb + e) * 1024 + ob + o] = tile[o][e];
    }
}

// ---- per-layer kernels ---------------------------------------------------

// fused x+y: grid 64 (2 batches each), block 256; thread owns 4 consecutive o.
// Writes its own xcol slice; y[b,o4..] = base+cb + sum_e xs[b][e]*W2t[e,o4..]
__global__ void k_yx2(int first, const int* __restrict__ tok, const float* __restrict__ emb,
                      const float* __restrict__ h, const float* __restrict__ pe2,
                      const float* __restrict__ W2t, const float* __restrict__ base,
                      const float* __restrict__ cb, float* __restrict__ xcol,
                      float* __restrict__ y) {
    int bq = blockIdx.x, t = threadIdx.x;
    __shared__ float xs[2][512];
    for (int j = t; j < 1024; j += 256) {
        int bb = j >> 9, e = j & 511;
        int b = bq * 2 + bb;
        float v = first ? emb[tok[b] * 512 + e] : h[b * 512 + e];
        float x = v + pe2[e];
        xs[bb][e] = x;
        xcol[b * 512 + e] = x;
    }
    __syncthreads();
    int o4 = t * 4;
    v4f bs = *(const v4f*)&base[o4];
    v4f cbs = *(const v4f*)&cb[o4];
    v4f a0 = bs + cbs, a1 = a0;
    #pragma unroll 4
    for (int e = 0; e < 512; ++e) {
        v4f w = *(const v4f*)&W2t[e * 1024 + o4];
        a0 += xs[0][e] * w;
        a1 += xs[1][e] * w;
    }
    int b0 = bq * 2;
    *(v4f*)&y[(size_t)b0 * 1024 + o4] = a0;
    *(v4f*)&y[(size_t)(b0 + 1) * 1024 + o4] = a1;
}

// partial scores: grid (8 hc, 128 b), block 256 = 4 waves; nt row streams.
__global__ void k_scores2(const float* __restrict__ y, const float* __restrict__ xcol,
                          const float* __restrict__ enc, float* __restrict__ part) {
    int hc = blockIdx.x, b = blockIdx.y, t = threadIdx.x;
    int w = t >> 6, lane = t & 63;
    __shared__ float dl[64];
    __shared__ float red[4 * 2048];
    if (t < 64) {
        int hg = hc * 64 + t;
        float ya = y[b * 1024 + hg];
        float yb_ = y[b * 1024 + 512 + hg];
        float g = ya / (1.0f + expf(-yb_));
        dl[t] = g + xcol[b * 512 + hg];
    }
    __syncthreads();
    v4f a[8];
    #pragma unroll
    for (int j = 0; j < 8; ++j) a[j] = (v4f)(0.f);
    const float* bp = enc + ((size_t)b * 512 + hc * 64 + w * 16) * 2048 + lane * 4;
    for (int r = 0; r < 16; ++r) {
        float dh = dl[w * 16 + r];
        const float* rp = bp + (size_t)r * 2048;
        #pragma unroll
        for (int j = 0; j < 8; ++j) {
            v4f v = ldnt4(rp + j * 256);
            a[j] += dh * v;
        }
    }
    #pragma unroll
    for (int j = 0; j < 8; ++j)
        *(v4f*)&red[w * 2048 + j * 256 + lane * 4] = a[j];
    __syncthreads();
    #pragma unroll
    for (int k = 0; k < 2; ++k) {
        int s = t * 4 + k * 1024;
        v4f s0 = *(const v4f*)&red[0 * 2048 + s];
        v4f s1 = *(const v4f*)&red[1 * 2048 + s];
        v4f s2 = *(const v4f*)&red[2 * 2048 + s];
        v4f s3 = *(const v4f*)&red[3 * 2048 + s];
        *(v4f*)&part[(size_t)hc * 262144 + b * 2048 + s] = (s0 + s1) + (s2 + s3);
    }
}

// sum 8 partials + softmax over S=2048 per batch; block 1024, 2 slots/thread
__global__ void k_softmax3(const float* __restrict__ part, float* __restrict__ attn) {
    int b = blockIdx.x, t = threadIdx.x;
    float a0 = 0.f, a1 = 0.f;
    #pragma unroll
    for (int hc = 0; hc < 8; ++hc) {
        const float* pp = part + (size_t)hc * 262144 + b * 2048;
        a0 += pp[t]; a1 += pp[t + 1024];
    }
    __shared__ float r[1024];
    r[t] = fmaxf(a0, a1); __syncthreads();
    for (int s = 512; s > 0; s >>= 1) { if (t < s) r[t] = fmaxf(r[t], r[t + s]); __syncthreads(); }
    float M = r[0]; __syncthreads();
    float e0 = expf(a0 - M), e1 = expf(a1 - M);
    r[t] = e0 + e1; __syncthreads();
    for (int s = 512; s > 0; s >>= 1) { if (t < s) r[t] += r[t + s]; __syncthreads(); }
    float inv = 1.0f / r[0];
    attn[b * 2048 + t] = e0 * inv;
    attn[b * 2048 + t + 1024] = e1 * inv;
}

// c[b,h] = sum_s attn[b,s]*enc_total[b,h,s]; h_out = glu(y) + c.
// block 512 = 8 waves, 8 h-rows; attn staged in LDS.
// MODE 0: f32 read. MODE 1: f32 read + fp16 nt-store cache. MODE 2: fp16 read.
template <int MODE>
__global__ void k_c3(const float* __restrict__ attn, const float* __restrict__ encf,
                     _Float16* __restrict__ e16, const float* __restrict__ y,
                     float* __restrict__ hbuf) {
    int t = threadIdx.x;                              // grid 8192
    int b  = blockIdx.x >> 6;
    int h0 = (blockIdx.x & 63) << 3;
    __shared__ float al[2048];
    for (int j = t; j < 2048; j += 512) al[j] = attn[b * 2048 + j];
    __syncthreads();
    int w = t >> 6, lane = t & 63;
    int hh = h0 + w;
    size_t rowoff = ((size_t)b * 512 + hh) * 2048;
    float acc = 0.f;
    #pragma unroll
    for (int it = 0; it < 8; ++it) {
        int s = it * 256 + lane * 4;
        v4f v;
        if (MODE == 2) {
            h4 x = __builtin_nontemporal_load((const h4*)(e16 + rowoff + s));
            v = (v4f){(float)x[0], (float)x[1], (float)x[2], (float)x[3]};
        } else {
            v = ldnt4(encf + rowoff + s);
            if (MODE == 1) {
                h4 x = {(_Float16)v[0], (_Float16)v[1], (_Float16)v[2], (_Float16)v[3]};
                __builtin_nontemporal_store(x, (h4*)(e16 + rowoff + s));
            }
        }
        float4 p = *(const float4*)&al[s];
        acc += p.x * v[0] + p.y * v[1] + p.z * v[2] + p.w * v[3];
    }
    #pragma unroll
    for (int off = 32; off > 0; off >>= 1) acc += __shfl_down(acc, off, 64);
    if (lane == 0) {
        float ya = y[b * 1024 + hh];
        float yb_ = y[b * 1024 + 512 + hh];
        float g = ya / (1.0f + expf(-yb_));
        hbuf[b * 512 + hh] = g + acc;
    }
}

// ---- epilogue (fused logits/log-softmax + softmax over H) ---------------

__global__ void k_epi(const float* __restrict__ h, const float* __restrict__ l2w,
                      const float* __restrict__ l2b, float* __restrict__ out) {
    int b = blockIdx.x, t = threadIdx.x;              // block 256
    __shared__ float hl[512];
    hl[t] = h[b * 512 + t]; hl[t + 256] = h[b * 512 + 256 + t];
    __syncthreads();
    float acc = 0.f;
    if (t < V_) {
        acc = l2b[t];
        for (int e = 0; e < 512; ++e) acc += hl[e] * l2w[t * 512 + e];
    }
    __shared__ float r[256];
    r[t] = (t < V_) ? acc : -1e30f; __syncthreads();
    for (int s = 128; s > 0; s >>= 1) { if (t < s) r[t] = fmaxf(r[t], r[t + s]); __syncthreads(); }
    float M = r[0]; __syncthreads();
    r[t] = (t < V_) ? expf(acc - M) : 0.f; __syncthreads();
    for (int s = 128; s > 0; s >>= 1) { if (t < s) r[t] += r[t + s]; __syncthreads(); }
    float L = M + logf(r[0]);
    if (t < V_) out[65536 + b * V_ + t] = acc - L;
    __syncthreads();
    float v0 = hl[t], v1 = hl[t + 256];
    r[t] = fmaxf(v0, v1); __syncthreads();
    for (int s = 128; s > 0; s >>= 1) { if (t < s) r[t] = fmaxf(r[t], r[t + s]); __syncthreads(); }
    float M2 = r[0]; __syncthreads();
    float e0 = expf(v0 - M2), e1 = expf(v1 - M2);
    r[t] = e0 + e1; __syncthreads();
    for (int s = 128; s > 0; s >>= 1) { if (t < s) r[t] += r[t + s]; __syncthreads(); }
    float inv = 1.0f / r[0];
    out[b * 512 + t] = e0 * inv;
    out[b * 512 + 256 + t] = e1 * inv;
}

// ---- launch --------------------------------------------------------------

extern "C" void kernel_launch(void* const* d_in, const int* in_sizes, int n_in,
                              void* d_out, int out_size, void* d_ws, size_t ws_size,
                              hipStream_t stream) {
    const float* enc_out = (const float*)d_in[0];   // [B,H,S] f32
    const float* enc_tot = (const float*)d_in[1];   // [B,H,S] f32
    const int*   tok     = (const int*)d_in[2];     // [B] int32
    const float* emb     = (const float*)d_in[4];   // [V,E] f32
    const float* conv_w  = (const float*)d_in[5];   // [1024,512,3] f32
    const float* conv_b  = (const float*)d_in[6];   // [1024] f32
    const float* l2w     = (const float*)d_in[7];   // [83,512] f32
    const float* l2b     = (const float*)d_in[8];   // [83] f32
    float* out = (float*)d_out;                     // 65536 + 10624 f32
    float* ws = (float*)d_ws;

    // ws layout (floats)
    float* W2t  = ws;                 // 524288
    float* base = W2t + 524288;       // 1024
    float* pe2  = base + 1024;        // 512
    float* x01i = pe2 + 512;          // 1536
    float* xcol = x01i + 1536;        // 65536
    float* yb   = xcol + 65536;       // 131072
    float* attn = yb + 131072;        // 262144
    float* part = attn + 262144;      // 2097152
    float* hbuf = part + 2097152;     // 65536
    size_t nfloats = 3148800;         // ~12.6 MB
    _Float16* e16 = (_Float16*)(ws + nfloats);      // 134217728 halfs = 268.4 MB
    bool cache16 = ws_size >= nfloats * 4 + (size_t)134217728 * 2;

    k_misc<<<1, 512, 0, stream>>>(emb, pe2, x01i);
    k_base3<<<256, 256, 0, stream>>>(conv_w, x01i, base);
    k_prep<<<dim3(16, 4), 256, 0, stream>>>(conv_w, W2t);

    for (int L = 0; L < 3; ++L) {
        k_yx2<<<64, 256, 0, stream>>>(L == 0 ? 1 : 0, tok, emb, hbuf, pe2,
                                      W2t, base, conv_b, xcol, yb);
        k_scores2<<<dim3(8, 128), 256, 0, stream>>>(yb, xcol, enc_out, part);
        k_softmax3<<<128, 1024, 0, stream>>>(part, attn);
        if (!cache16)
            k_c3<0><<<8192, 512, 0, stream>>>(attn, enc_tot, e16, yb, hbuf);
        else if (L == 0)
            k_c3<1><<<8192, 512, 0, stream>>>(attn, enc_tot, e16, yb, hbuf);
        else
            k_c3<2><<<8192, 512, 0, stream>>>(attn, enc_tot, e16, yb, hbuf);
    }

    k_epi<<<128, 256, 0, stream>>>(hbuf, l2w, l2b, out);
}